// Round 1
// baseline (438.389 us; speedup 1.0000x reference)
//
#include <hip/hip_runtime.h>
#include <math.h>

// Problem constants
#define B_ 512
#define I_ 8
#define C_ 1152
#define U_ 10
#define O_ 16
#define K_ (I_*C_)        // 9216  (flattened (i,c) contraction dim)
#define UO_ (U_*O_)       // 160
#define KSPLIT 16
#define KCHUNK (K_/KSPLIT) // 576

// Persistent device scratch (overwritten every call -> deterministic)
__device__ float g_b[C_*U_];               // routing logits [c][u]
__device__ float g_cw[C_*U_];              // softmax(b) over u   [c][u]
__device__ float g_Wt[UO_*I_*C_];          // W transposed: [u,o,i][c]  (== [uo][k])
__device__ float g_Wc[UO_*I_*C_];          // cw-weighted W: [uo][k]
__device__ float g_spart[KSPLIT][B_*UO_];  // split-K partials of s
__device__ float g_s[B_*UO_];              // s[b][uo]
__device__ float g_v[B_*UO_];              // v[b][uo]
__device__ float g_T[K_*UO_];              // T[k][uo] = sum_b x[b,k]*v[b,uo]

__global__ void k_zero_b() {
    int g = blockIdx.x*256 + threadIdx.x;
    if (g < C_*U_) g_b[g] = 0.f;
}

// W flat: [c][u][o][i] = c*1280 + (u*128+o*8+i).  Pure 1152x1280 transpose -> g_Wt[uoi][c].
__global__ __launch_bounds__(256) void k_transposeW(const float* __restrict__ W) {
    __shared__ float tile[32][33];
    int r0 = blockIdx.x*32;   // uoi
    int c0 = blockIdx.y*32;   // c
    int tx = threadIdx.x & 31, ty = threadIdx.x >> 5;
    #pragma unroll
    for (int j = 0; j < 4; j++) {
        int c = c0 + ty + 8*j;
        tile[ty+8*j][tx] = W[c*1280 + r0 + tx];
    }
    __syncthreads();
    #pragma unroll
    for (int j = 0; j < 4; j++) {
        int r = r0 + ty + 8*j;
        g_Wt[r*C_ + c0 + tx] = tile[tx][ty+8*j];
    }
}

// softmax over u (10) per channel c
__global__ void k_softmax() {
    int c = blockIdx.x*256 + threadIdx.x;
    if (c >= C_) return;
    float bv[U_];
    float m = -1e30f;
    #pragma unroll
    for (int u = 0; u < U_; u++) { bv[u] = g_b[c*U_+u]; m = fmaxf(m, bv[u]); }
    float sum = 0.f;
    #pragma unroll
    for (int u = 0; u < U_; u++) { bv[u] = expf(bv[u]-m); sum += bv[u]; }
    float inv = 1.f/sum;
    #pragma unroll
    for (int u = 0; u < U_; u++) g_cw[c*U_+u] = bv[u]*inv;
}

// Wc[uoi][c] = cw[c][u] * Wt[uoi][c], float4 over c. 368640 float4 elems, grid=1440.
__global__ void k_buildWc() {
    int g = blockIdx.x*256 + threadIdx.x;
    const float4* wt4 = (const float4*)g_Wt;
    float4* wc4 = (float4*)g_Wc;
    int row = g / (C_/4);      // uoi  (u = row>>7)
    int c4  = g % (C_/4);
    int u = row >> 7;
    float4 w = wt4[g];
    int cb = c4*4;
    w.x *= g_cw[(cb+0)*U_+u];
    w.y *= g_cw[(cb+1)*U_+u];
    w.z *= g_cw[(cb+2)*U_+u];
    w.w *= g_cw[(cb+3)*U_+u];
    wc4[g] = w;
}

// s[b][uo] = sum_k x[b][k]*Wc[uo][k].  M=512,N=160,K=9216, split-K into 16.
__global__ __launch_bounds__(256) void k_sgemm(const float* __restrict__ x) {
    __shared__ float xs[32][33];
    __shared__ float ws[32][33];
    int m0 = blockIdx.x*32;
    int n0 = blockIdx.y*32;
    int kz = blockIdx.z;
    int k0 = kz*KCHUNK;
    int tx = threadIdx.x & 31, ty = threadIdx.x >> 5;
    float acc[4] = {0.f,0.f,0.f,0.f};
    for (int kk0 = 0; kk0 < KCHUNK; kk0 += 32) {
        #pragma unroll
        for (int j = 0; j < 4; j++) {
            int r = ty + 8*j;
            xs[r][tx] = x[(m0+r)*K_ + k0+kk0+tx];
            ws[r][tx] = g_Wc[(n0+r)*K_ + k0+kk0+tx];
        }
        __syncthreads();
        #pragma unroll
        for (int kk = 0; kk < 32; kk++) {
            float wv = ws[tx][kk];
            #pragma unroll
            for (int j = 0; j < 4; j++)
                acc[j] += xs[ty+8*j][kk] * wv;
        }
        __syncthreads();
    }
    #pragma unroll
    for (int j = 0; j < 4; j++)
        g_spart[kz][(m0+ty+8*j)*UO_ + n0+tx] = acc[j];
}

__global__ void k_reduce_s() {
    int g = blockIdx.x*256 + threadIdx.x;  // 81920 total
    float sum = 0.f;
    #pragma unroll
    for (int ks = 0; ks < KSPLIT; ks++) sum += g_spart[ks][g];
    g_s[g] = sum;
}

// squash over O=16 per (b,u) row; optionally write final output
__global__ void k_squash(float* __restrict__ out, int write_out) {
    int g = blockIdx.x*256 + threadIdx.x;
    if (g >= B_*U_) return;
    int base = g*O_;
    float t[O_];
    float norm = 0.f;
    #pragma unroll
    for (int o = 0; o < O_; o++) { t[o] = g_s[base+o]; norm += t[o]*t[o]; }
    float f = norm / ((1.f+norm)*sqrtf(norm));
    #pragma unroll
    for (int o = 0; o < O_; o++) {
        float vv = t[o]*f;
        g_v[base+o] = vv;
        if (write_out) out[base+o] = vv;
    }
}

// T[k][uo] = sum_b x[b][k]*v[b][uo].  M=9216,N=160,K=512.
__global__ __launch_bounds__(256) void k_tgemm(const float* __restrict__ x) {
    __shared__ float xs[32][33];
    __shared__ float vs[32][33];
    int m0 = blockIdx.x*32;   // k rows
    int n0 = blockIdx.y*32;   // uo
    int tx = threadIdx.x & 31, ty = threadIdx.x >> 5;
    float acc[4] = {0.f,0.f,0.f,0.f};
    for (int b0 = 0; b0 < B_; b0 += 32) {
        #pragma unroll
        for (int j = 0; j < 4; j++) {
            int r = ty + 8*j;
            xs[r][tx] = x[(b0+r)*K_ + m0+tx];
            vs[r][tx] = g_v[(b0+r)*UO_ + n0+tx];
        }
        __syncthreads();
        #pragma unroll
        for (int kk = 0; kk < 32; kk++) {
            float vv = vs[kk][tx];
            #pragma unroll
            for (int j = 0; j < 4; j++)
                acc[j] += xs[kk][ty+8*j] * vv;
        }
        __syncthreads();
    }
    #pragma unroll
    for (int j = 0; j < 4; j++)
        g_T[(m0+ty+8*j)*UO_ + n0+tx] = acc[j];
}

// b[c][u] += (1/B) * sum_{o,i} Wt[(u,o,i)][c] * T[(i,c)][(u,o)]
__global__ void k_bupdate() {
    int g = blockIdx.x*256 + threadIdx.x;
    if (g >= C_*U_) return;
    int u = g / C_;
    int c = g % C_;
    float sum = 0.f;
    for (int o = 0; o < O_; o++) {
        #pragma unroll
        for (int i = 0; i < I_; i++) {
            sum += g_Wt[((u*O_+o)*I_+i)*C_ + c] * g_T[(i*C_+c)*UO_ + u*O_+o];
        }
    }
    g_b[c*U_+u] += sum * (1.f/(float)B_);
}

extern "C" void kernel_launch(void* const* d_in, const int* in_sizes, int n_in,
                              void* d_out, int out_size, void* d_ws, size_t ws_size,
                              hipStream_t stream) {
    const float* x = (const float*)d_in[0];
    const float* W = (const float*)d_in[1];
    float* out = (float*)d_out;

    k_zero_b<<<dim3(45), dim3(256), 0, stream>>>();
    k_transposeW<<<dim3(40,36), dim3(256), 0, stream>>>(W);

    for (int t = 0; t < 3; t++) {
        k_softmax<<<dim3(5), dim3(256), 0, stream>>>();
        k_buildWc<<<dim3(1440), dim3(256), 0, stream>>>();
        k_sgemm<<<dim3(16,5,KSPLIT), dim3(256), 0, stream>>>(x);
        k_reduce_s<<<dim3(320), dim3(256), 0, stream>>>();
        k_squash<<<dim3(20), dim3(256), 0, stream>>>(out, t == 2 ? 1 : 0);
        if (t < 2) {
            k_tgemm<<<dim3(288,5), dim3(256), 0, stream>>>(x);
            k_bupdate<<<dim3(45), dim3(256), 0, stream>>>();
        }
    }
}

// Round 2
// 240.909 us; speedup vs baseline: 1.8197x; 1.8197x over previous
//
#include <hip/hip_runtime.h>
#include <math.h>

// Problem constants
#define B_ 512
#define I_ 8
#define C_ 1152
#define U_ 10
#define O_ 16
#define K_ (I_*C_)        // 9216  (flattened (i,c) contraction, k = i*1152 + c)
#define UO_ (U_*O_)       // 160
#define KSPLIT 16
#define KCHUNK (K_/KSPLIT) // 576 = 18 * 32

typedef short bf16x8 __attribute__((ext_vector_type(8)));
typedef float f32x4 __attribute__((ext_vector_type(4)));

// ---- persistent device scratch (fully overwritten every call) ----
__device__ __attribute__((aligned(16))) unsigned short g_xb[B_*K_];   // bf16 x  [b][k]
__device__ __attribute__((aligned(16))) unsigned short g_xT[K_*B_];   // bf16 x^T [k][b]
__device__ __attribute__((aligned(16))) float g_Wt[UO_*I_*C_];        // fp32 W^T [uoi][c]
__device__ __attribute__((aligned(16))) unsigned short g_Wcb[UO_*K_]; // bf16 Wc [uo][k]
__device__ float g_b[C_*U_];                                          // logits [c][u]
__device__ float g_cw[C_*U_];                                         // softmax weights [c][u]
__device__ __attribute__((aligned(16))) float g_spart[KSPLIT][B_*UO_];
__device__ __attribute__((aligned(16))) unsigned short g_vT[UO_*B_];  // bf16 v^T [uo][b]
__device__ __attribute__((aligned(16))) float g_T[K_*UO_];            // fp32 T [k][uo]

__device__ __forceinline__ unsigned short f2bf(float f) {
    unsigned u = __builtin_bit_cast(unsigned, f);
    unsigned r = (u + 0x7FFFu + ((u >> 16) & 1u)) >> 16;
    return (unsigned short)r;
}

// ---- one-time: convert x to bf16 in both [b][k] and [k][b] layouts ----
__global__ __launch_bounds__(256) void k_xprep(const float* __restrict__ x) {
    __shared__ unsigned short tile[32][33];
    int b0 = blockIdx.x*32;
    int k0 = blockIdx.y*32;
    int tx = threadIdx.x & 31, ty = threadIdx.x >> 5;
    #pragma unroll
    for (int j = 0; j < 4; j++) {
        int r = ty + 8*j;
        unsigned short h = f2bf(x[(b0+r)*K_ + k0+tx]);
        tile[r][tx] = h;
        g_xb[(b0+r)*K_ + k0+tx] = h;
    }
    __syncthreads();
    #pragma unroll
    for (int j = 0; j < 4; j++) {
        int r = ty + 8*j;   // k within tile
        g_xT[(k0+r)*B_ + b0+tx] = tile[tx][r];
    }
}

// ---- one-time: W [c][uoi] -> Wt [uoi][c]  (1152 x 1280 transpose) ----
__global__ __launch_bounds__(256) void k_transposeW(const float* __restrict__ W) {
    __shared__ float tile[32][33];
    int r0 = blockIdx.x*32;   // uoi
    int c0 = blockIdx.y*32;   // c
    int tx = threadIdx.x & 31, ty = threadIdx.x >> 5;
    #pragma unroll
    for (int j = 0; j < 4; j++) {
        int c = c0 + ty + 8*j;
        tile[ty+8*j][tx] = W[c*1280 + r0 + tx];
    }
    __syncthreads();
    #pragma unroll
    for (int j = 0; j < 4; j++) {
        int r = r0 + ty + 8*j;
        g_Wt[r*C_ + c0 + tx] = tile[tx][ty+8*j];
    }
}

// ---- per-iter (t>0): softmax over u per channel c ----
__global__ void k_softmax() {
    int c = blockIdx.x*256 + threadIdx.x;
    if (c >= C_) return;
    float bv[U_];
    float m = -1e30f;
    #pragma unroll
    for (int u = 0; u < U_; u++) { bv[u] = g_b[c*U_+u]; m = fmaxf(m, bv[u]); }
    float sum = 0.f;
    #pragma unroll
    for (int u = 0; u < U_; u++) { bv[u] = expf(bv[u]-m); sum += bv[u]; }
    float inv = 1.f/sum;
    #pragma unroll
    for (int u = 0; u < U_; u++) g_cw[c*U_+u] = bv[u]*inv;
}

// ---- per-iter: Wc_bf16[uoi][c] = cw[c][u] * Wt[uoi][c] ----
__global__ void k_buildWc(int uniform) {
    int g = blockIdx.x*256 + threadIdx.x;          // over 1280*288 float4 groups
    const float4* wt4 = (const float4*)g_Wt;
    int row = g / (C_/4);      // uoi,  u = row>>7
    int c4  = g % (C_/4);
    int u = row >> 7;
    float4 w = wt4[g];
    int cb = c4*4;
    float w0, w1, w2, w3;
    if (uniform) { w0 = w1 = w2 = w3 = 0.1f; }
    else {
        w0 = g_cw[(cb+0)*U_+u]; w1 = g_cw[(cb+1)*U_+u];
        w2 = g_cw[(cb+2)*U_+u]; w3 = g_cw[(cb+3)*U_+u];
    }
    unsigned short h0 = f2bf(w.x*w0), h1 = f2bf(w.y*w1), h2 = f2bf(w.z*w2), h3 = f2bf(w.w*w3);
    ushort4 out; out.x = h0; out.y = h1; out.z = h2; out.w = h3;
    ((ushort4*)g_Wcb)[g] = out;
}

// ---- s-GEMM: spart[kz][b][uo] = sum_{k in chunk} x[b][k] * Wc[uo][k]
// MFMA 16x16x32 bf16; 1 wave/block; wave tile 16(M) x 32(N).
__global__ __launch_bounds__(64) void k_sgemm() {
    int lane = threadIdx.x;
    int m0 = blockIdx.x * 16;
    int n0 = blockIdx.y * 32;
    int kz = blockIdx.z;
    int k0 = kz * KCHUNK;

    int ra = lane & 15;          // A row / B col
    int ko = (lane >> 4) * 8;    // k offset within 32

    const unsigned short* pa  = g_xb  + (m0 + ra)*K_ + k0 + ko;
    const unsigned short* pb0 = g_Wcb + (n0 + ra)*K_ + k0 + ko;
    const unsigned short* pb1 = g_Wcb + (n0 + 16 + ra)*K_ + k0 + ko;

    f32x4 acc0 = {0.f,0.f,0.f,0.f};
    f32x4 acc1 = {0.f,0.f,0.f,0.f};
    #pragma unroll 9
    for (int s = 0; s < KCHUNK/32; s++) {
        bf16x8 a  = *(const bf16x8*)pa;
        bf16x8 b0 = *(const bf16x8*)pb0;
        bf16x8 b1 = *(const bf16x8*)pb1;
        acc0 = __builtin_amdgcn_mfma_f32_16x16x32_bf16(a, b0, acc0, 0, 0, 0);
        acc1 = __builtin_amdgcn_mfma_f32_16x16x32_bf16(a, b1, acc1, 0, 0, 0);
        pa += 32; pb0 += 32; pb1 += 32;
    }
    int row = (lane >> 4) * 4;   // + r
    int col = lane & 15;
    float* outp = &g_spart[kz][0];
    #pragma unroll
    for (int r = 0; r < 4; r++) {
        outp[(m0+row+r)*UO_ + n0 + col]      = acc0[r];
        outp[(m0+row+r)*UO_ + n0 + 16 + col] = acc1[r];
    }
}

// ---- reduce split-K partials + squash; write vT (bf16) and optionally out ----
__global__ __launch_bounds__(256) void k_squash(float* __restrict__ out, int write_out) {
    int g = blockIdx.x*256 + threadIdx.x;    // 5120 = 512*10
    if (g >= B_*U_) return;
    int u = g >> 9;          // g / 512
    int b = g & 511;
    float t[O_];
    #pragma unroll
    for (int o = 0; o < O_; o++) t[o] = 0.f;
    #pragma unroll
    for (int ks = 0; ks < KSPLIT; ks++) {
        const f32x4* p = (const f32x4*)&g_spart[ks][b*UO_ + u*O_];
        #pragma unroll
        for (int q = 0; q < 4; q++) {
            f32x4 v4 = p[q];
            t[q*4+0] += v4[0]; t[q*4+1] += v4[1]; t[q*4+2] += v4[2]; t[q*4+3] += v4[3];
        }
    }
    float norm = 0.f;
    #pragma unroll
    for (int o = 0; o < O_; o++) norm += t[o]*t[o];
    float f = norm / ((1.f + norm) * sqrtf(norm));
    #pragma unroll
    for (int o = 0; o < O_; o++) {
        float vv = t[o] * f;
        g_vT[(u*O_+o)*B_ + b] = f2bf(vv);
        if (write_out) out[(b*U_+u)*O_ + o] = vv;
    }
}

// ---- T-GEMM: T[k][uo] = sum_b xT[k][b] * vT[uo][b]   (M=9216, N=160, K=512)
__global__ __launch_bounds__(64) void k_tgemm() {
    int lane = threadIdx.x;
    int m0 = blockIdx.x * 16;    // k-dim rows
    int n0 = blockIdx.y * 32;

    int ra = lane & 15;
    int ko = (lane >> 4) * 8;

    const unsigned short* pa  = g_xT + (m0 + ra)*B_ + ko;
    const unsigned short* pb0 = g_vT + (n0 + ra)*B_ + ko;
    const unsigned short* pb1 = g_vT + (n0 + 16 + ra)*B_ + ko;

    f32x4 acc0 = {0.f,0.f,0.f,0.f};
    f32x4 acc1 = {0.f,0.f,0.f,0.f};
    #pragma unroll 8
    for (int s = 0; s < B_/32; s++) {
        bf16x8 a  = *(const bf16x8*)pa;
        bf16x8 b0 = *(const bf16x8*)pb0;
        bf16x8 b1 = *(const bf16x8*)pb1;
        acc0 = __builtin_amdgcn_mfma_f32_16x16x32_bf16(a, b0, acc0, 0, 0, 0);
        acc1 = __builtin_amdgcn_mfma_f32_16x16x32_bf16(a, b1, acc1, 0, 0, 0);
        pa += 32; pb0 += 32; pb1 += 32;
    }
    int row = (lane >> 4) * 4;
    int col = lane & 15;
    #pragma unroll
    for (int r = 0; r < 4; r++) {
        g_T[(m0+row+r)*UO_ + n0 + col]      = acc0[r];
        g_T[(m0+row+r)*UO_ + n0 + 16 + col] = acc1[r];
    }
}

// ---- b[c][u] (+)= (1/B) * sum_{o,i} Wt[(u,o,i)][c] * T[(i,c)][(u,o)] ----
__global__ void k_bupdate(int first) {
    int g = blockIdx.x*256 + threadIdx.x;
    if (g >= C_*U_) return;
    int u = g / C_;
    int c = g % C_;
    float sum = 0.f;
    for (int o = 0; o < O_; o++) {
        #pragma unroll
        for (int i = 0; i < I_; i++) {
            sum += g_Wt[((u*O_+o)*I_+i)*C_ + c] * g_T[(i*C_+c)*UO_ + u*O_+o];
        }
    }
    sum *= (1.f/(float)B_);
    if (first) g_b[c*U_+u] = sum;
    else       g_b[c*U_+u] += sum;
}

extern "C" void kernel_launch(void* const* d_in, const int* in_sizes, int n_in,
                              void* d_out, int out_size, void* d_ws, size_t ws_size,
                              hipStream_t stream) {
    const float* x = (const float*)d_in[0];
    const float* W = (const float*)d_in[1];
    float* out = (float*)d_out;

    k_xprep<<<dim3(16,288), dim3(256), 0, stream>>>(x);
    k_transposeW<<<dim3(40,36), dim3(256), 0, stream>>>(W);

    for (int t = 0; t < 3; t++) {
        if (t > 0) k_softmax<<<dim3(5), dim3(256), 0, stream>>>();
        k_buildWc<<<dim3(1440), dim3(256), 0, stream>>>(t == 0 ? 1 : 0);
        k_sgemm<<<dim3(32,5,KSPLIT), dim3(64), 0, stream>>>();
        k_squash<<<dim3(20), dim3(256), 0, stream>>>(out, t == 2 ? 1 : 0);
        if (t < 2) {
            k_tgemm<<<dim3(576,5), dim3(64), 0, stream>>>();
            k_bupdate<<<dim3(45), dim3(256), 0, stream>>>(t == 0 ? 1 : 0);
        }
    }
}

// Round 3
// 192.481 us; speedup vs baseline: 2.2776x; 1.2516x over previous
//
#include <hip/hip_runtime.h>
#include <math.h>

// Problem constants
#define B_ 512
#define I_ 8
#define C_ 1152
#define U_ 10
#define O_ 16
#define K_ (I_*C_)        // 9216 (k = i*1152 + c)
#define UO_ (U_*O_)       // 160
#define KSPLIT 16
#define KCHUNK (K_/KSPLIT) // 576 = 18*32

typedef short bf16x8 __attribute__((ext_vector_type(8)));
typedef float f32x4 __attribute__((ext_vector_type(4)));

// ---- persistent device scratch (fully overwritten every call) ----
__device__ __attribute__((aligned(16))) unsigned short g_xb[B_*K_];   // bf16 x  [b][k]
__device__ __attribute__((aligned(16))) unsigned short g_xT[K_*B_];   // bf16 x^T [k][b]
__device__ __attribute__((aligned(16))) float g_Wt[UO_*I_*C_];        // fp32 W^T [uoi][c]
__device__ __attribute__((aligned(16))) unsigned short g_Wcb[UO_*K_]; // bf16 Wc [uo][k]
__device__ float g_b[C_*U_];                                          // logits [c][u]
__device__ float g_cw[C_*U_];                                         // softmax weights [c][u]
__device__ __attribute__((aligned(16))) float g_spart[KSPLIT][B_*UO_];
__device__ __attribute__((aligned(16))) unsigned short g_vT[UO_*B_];  // bf16 v^T [uo][b]
__device__ __attribute__((aligned(16))) float g_T[K_*UO_];            // fp32 T [k][uo]

__device__ __forceinline__ unsigned short f2bf(float f) {
    unsigned u = __builtin_bit_cast(unsigned, f);
    unsigned r = (u + 0x7FFFu + ((u >> 16) & 1u)) >> 16;
    return (unsigned short)r;
}

// ---- one-time prep: x -> bf16 [b][k] and [k][b]; W -> fp32 W^T [uoi][c] ----
__global__ __launch_bounds__(256) void k_prep(const float* __restrict__ x,
                                              const float* __restrict__ W) {
    __shared__ float tile[32][33];
    int blk = blockIdx.x;
    int tx = threadIdx.x & 31, ty = threadIdx.x >> 5;
    if (blk < 4608) {                       // x: 16 (b) x 288 (k) tiles of 32x32
        int b0 = (blk & 15) * 32;
        int k0 = (blk >> 4) * 32;
        #pragma unroll
        for (int j = 0; j < 4; j++) {
            int r = ty + 8*j;
            float f = x[(b0+r)*K_ + k0+tx];
            tile[r][tx] = f;
            g_xb[(b0+r)*K_ + k0+tx] = f2bf(f);
        }
        __syncthreads();
        #pragma unroll
        for (int j = 0; j < 4; j++) {
            int r = ty + 8*j;               // k within tile
            g_xT[(k0+r)*B_ + b0+tx] = f2bf(tile[tx][r]);
        }
    } else {                                // W: 40 (uoi) x 36 (c) tiles of 32x32
        int q = blk - 4608;
        int r0 = (q % 40) * 32;             // uoi
        int c0 = (q / 40) * 32;             // c
        #pragma unroll
        for (int j = 0; j < 4; j++)
            tile[ty+8*j][tx] = W[(c0+ty+8*j)*1280 + r0+tx];
        __syncthreads();
        #pragma unroll
        for (int j = 0; j < 4; j++)
            g_Wt[(r0+ty+8*j)*C_ + c0+tx] = tile[tx][ty+8*j];
    }
}

// ---- per-iter: Wc_bf16[uoi][c] = cw[c][u] * Wt[uoi][c] ----
__global__ __launch_bounds__(256) void k_buildWc(int uniform) {
    int g = blockIdx.x*256 + threadIdx.x;   // 1280*288 float4 groups
    const float4* wt4 = (const float4*)g_Wt;
    int row = g / (C_/4);                   // uoi, u = row>>7
    int c4  = g % (C_/4);
    int u = row >> 7;
    float4 w = wt4[g];
    int cb = c4*4;
    float w0, w1, w2, w3;
    if (uniform) { w0 = w1 = w2 = w3 = 0.1f; }
    else {
        w0 = g_cw[(cb+0)*U_+u]; w1 = g_cw[(cb+1)*U_+u];
        w2 = g_cw[(cb+2)*U_+u]; w3 = g_cw[(cb+3)*U_+u];
    }
    ushort4 o;
    o.x = f2bf(w.x*w0); o.y = f2bf(w.y*w1); o.z = f2bf(w.z*w2); o.w = f2bf(w.w*w3);
    ((ushort4*)g_Wcb)[g] = o;
}

// ---- s-GEMM: spart[kz][b][uo] = sum_k x[b][k]*Wc[uo][k]
// 4 waves/block (M=64 block tile), wave tile 16x32, MFMA 16x16x32 bf16
__global__ __launch_bounds__(256) void k_sgemm() {
    int lane = threadIdx.x & 63, wid = threadIdx.x >> 6;
    int m0 = blockIdx.x*64 + wid*16;
    int n0 = blockIdx.y*32;
    int k0 = blockIdx.z*KCHUNK;
    int ra = lane & 15;
    int ko = (lane >> 4) * 8;
    const unsigned short* pa  = g_xb  + (m0 + ra)*K_ + k0 + ko;
    const unsigned short* pb0 = g_Wcb + (n0 + ra)*K_ + k0 + ko;
    const unsigned short* pb1 = pb0 + 16*K_;
    f32x4 acc0 = {0.f,0.f,0.f,0.f};
    f32x4 acc1 = {0.f,0.f,0.f,0.f};
    #pragma unroll 9
    for (int s = 0; s < KCHUNK/32; s++) {
        bf16x8 a  = *(const bf16x8*)pa;
        bf16x8 b0 = *(const bf16x8*)pb0;
        bf16x8 b1 = *(const bf16x8*)pb1;
        acc0 = __builtin_amdgcn_mfma_f32_16x16x32_bf16(a, b0, acc0, 0, 0, 0);
        acc1 = __builtin_amdgcn_mfma_f32_16x16x32_bf16(a, b1, acc1, 0, 0, 0);
        pa += 32; pb0 += 32; pb1 += 32;
    }
    int row = (lane >> 4) * 4;
    int col = lane & 15;
    float* outp = &g_spart[blockIdx.z][0];
    #pragma unroll
    for (int r = 0; r < 4; r++) {
        outp[(m0+row+r)*UO_ + n0 + col]      = acc0[r];
        outp[(m0+row+r)*UO_ + n0 + 16 + col] = acc1[r];
    }
}

// ---- reduce split-K + squash; write vT (bf16), optionally final out ----
__global__ __launch_bounds__(256) void k_squash(float* __restrict__ out, int write_out) {
    int g = blockIdx.x*256 + threadIdx.x;   // 5120 = 512*10
    if (g >= B_*U_) return;
    int u = g >> 9;
    int b = g & 511;
    float t[O_];
    #pragma unroll
    for (int o = 0; o < O_; o++) t[o] = 0.f;
    #pragma unroll
    for (int ks = 0; ks < KSPLIT; ks++) {
        const f32x4* p = (const f32x4*)&g_spart[ks][b*UO_ + u*O_];
        #pragma unroll
        for (int q = 0; q < 4; q++) {
            f32x4 v4 = p[q];
            t[q*4+0] += v4[0]; t[q*4+1] += v4[1]; t[q*4+2] += v4[2]; t[q*4+3] += v4[3];
        }
    }
    float norm = 0.f;
    #pragma unroll
    for (int o = 0; o < O_; o++) norm += t[o]*t[o];
    float f = norm / ((1.f + norm) * sqrtf(norm));
    #pragma unroll
    for (int o = 0; o < O_; o++) {
        float vv = t[o] * f;
        g_vT[(u*O_+o)*B_ + b] = f2bf(vv);
        if (write_out) out[(b*U_+u)*O_ + o] = vv;
    }
}

// ---- T-GEMM: T[k][uo] = sum_b xT[k][b]*vT[uo][b]  (M=9216,N=160,K=512) ----
__global__ __launch_bounds__(256) void k_tgemm() {
    int lane = threadIdx.x & 63, wid = threadIdx.x >> 6;
    int m0 = blockIdx.x*64 + wid*16;
    int n0 = blockIdx.y*32;
    int ra = lane & 15;
    int ko = (lane >> 4) * 8;
    const unsigned short* pa  = g_xT + (m0 + ra)*B_ + ko;
    const unsigned short* pb0 = g_vT + (n0 + ra)*B_ + ko;
    const unsigned short* pb1 = pb0 + 16*B_;
    f32x4 acc0 = {0.f,0.f,0.f,0.f};
    f32x4 acc1 = {0.f,0.f,0.f,0.f};
    #pragma unroll 8
    for (int s = 0; s < B_/32; s++) {
        bf16x8 a  = *(const bf16x8*)pa;
        bf16x8 b0 = *(const bf16x8*)pb0;
        bf16x8 b1 = *(const bf16x8*)pb1;
        acc0 = __builtin_amdgcn_mfma_f32_16x16x32_bf16(a, b0, acc0, 0, 0, 0);
        acc1 = __builtin_amdgcn_mfma_f32_16x16x32_bf16(a, b1, acc1, 0, 0, 0);
        pa += 32; pb0 += 32; pb1 += 32;
    }
    int row = (lane >> 4) * 4;
    int col = lane & 15;
    #pragma unroll
    for (int r = 0; r < 4; r++) {
        g_T[(m0+row+r)*UO_ + n0 + col]      = acc0[r];
        g_T[(m0+row+r)*UO_ + n0 + 16 + col] = acc1[r];
    }
}

// ---- b-update + fused softmax for next iteration; one block per channel c ----
// agree[c,u] = (1/B) sum_{o,i} W[c,u,o,i] * T[(i,c)][(u,o)]
__global__ __launch_bounds__(192) void k_bupdate(const float* __restrict__ W, int first) {
    __shared__ float Ts[I_][UO_];
    __shared__ float bl[U_];
    int c = blockIdx.x;
    int tid = threadIdx.x;
    for (int idx = tid; idx < I_*UO_; idx += 192) {
        int i = idx / UO_, j = idx - i*UO_;
        Ts[i][j] = g_T[(i*C_ + c)*UO_ + j];
    }
    __syncthreads();
    if (tid < 160) {
        int u = tid >> 4, h = tid & 15;     // h = o
        const float* wp = W + c*1280 + u*128 + h*8;
        float sum = 0.f;
        #pragma unroll
        for (int i = 0; i < I_; i++) sum += wp[i] * Ts[i][u*16 + h];
        #pragma unroll
        for (int d = 8; d >= 1; d >>= 1) sum += __shfl_down(sum, d, 16);
        if (h == 0) {
            float val = sum * (1.f/512.f);
            if (!first) val += g_b[c*U_ + u];
            g_b[c*U_ + u] = val;
            bl[u] = val;
        }
    }
    __syncthreads();
    if (tid == 0) {
        float m = bl[0];
        #pragma unroll
        for (int u = 1; u < U_; u++) m = fmaxf(m, bl[u]);
        float e[U_]; float s = 0.f;
        #pragma unroll
        for (int u = 0; u < U_; u++) { e[u] = expf(bl[u]-m); s += e[u]; }
        float inv = 1.f/s;
        #pragma unroll
        for (int u = 0; u < U_; u++) g_cw[c*U_+u] = e[u]*inv;
    }
}

extern "C" void kernel_launch(void* const* d_in, const int* in_sizes, int n_in,
                              void* d_out, int out_size, void* d_ws, size_t ws_size,
                              hipStream_t stream) {
    const float* x = (const float*)d_in[0];
    const float* W = (const float*)d_in[1];
    float* out = (float*)d_out;

    k_prep<<<dim3(6048), dim3(256), 0, stream>>>(x, W);

    for (int t = 0; t < 3; t++) {
        k_buildWc<<<dim3(1440), dim3(256), 0, stream>>>(t == 0 ? 1 : 0);
        k_sgemm<<<dim3(8,5,KSPLIT), dim3(256), 0, stream>>>();
        k_squash<<<dim3(20), dim3(256), 0, stream>>>(out, t == 2 ? 1 : 0);
        if (t < 2) {
            k_tgemm<<<dim3(144,5), dim3(256), 0, stream>>>();
            k_bupdate<<<dim3(1152), dim3(192), 0, stream>>>(W, t == 0 ? 1 : 0);
        }
    }
}